// Round 6
// baseline (75.802 us; speedup 1.0000x reference)
//
#include <hip/hip_runtime.h>
#include <math.h>

// Preisach hysteresis, two kernels:
//  1) build_table (1 block x 512 threads): 2D prefix-sum density table built
//     in LDS, written once to global d_ws, plus per-64-chunk up-move-max /
//     down-move-min stats. 512 threads = 2 waves/SIMD -> 256-VGPR cap, so the
//     register-array scan phases (v[26]/v[13]) do NOT spill (the 1024-thread
//     version was capped at 128 VGPRs and spilled -> 57 us).
//  2) hyst_main (wave per t, no LDS): exact backward-record scan with
//     parallel chunk filter; table lookups deferred and issued
//     one-record-per-lane in parallel (no serial L2-latency chain).
//
// Table: C[a][b] = sum_{alpha_idx<a, beta_idx<b, beta<=alpha} softplus(raw),
// a,b in [0,L], row-major stride SP=202. packed p(i,j)=L*i-i(i-1)/2+(j-i).

__device__ __forceinline__ float softplus_f(float x) {
    return fmaxf(x, 0.0f) + log1pf(expf(-fabsf(x)));
}

__global__ __launch_bounds__(512, 2) void build_table(
    const float* __restrict__ h,
    const float* __restrict__ raw,
    float* __restrict__ Cg,      // W*SP floats
    float* __restrict__ statg,   // 2*nc floats
    int T, int L, int n)
{
    extern __shared__ float S[];
    const int W  = L + 1;            // 201
    const int SP = (W + 1) & ~1;     // 202
    const int nc = (T + 63) >> 6;

    const int tid  = threadIdx.x;
    const int lane = tid & 63;
    const int wid  = tid >> 6;            // 0..7
    const int nwv  = blockDim.x >> 6;     // 8
    const int r16  = lane & 15;
    const int seg  = lane >> 4;           // 0..3

    // ---- per-chunk up-move max / down-move min -> global ----
    for (int c = wid; c < nc; c += nwv) {
        const int i = (c << 6) + lane;
        const bool inb = (i < T);
        const float hv = inb ? h[i] : 0.0f;
        const float hp = (inb && i > 0) ? h[i - 1] : 0.0f;
        float mu = (inb && hv > hp) ? hv : -1.0f;
        float md = (inb && hv < hp) ? hv : 2.0f;
        for (int o = 1; o < 64; o <<= 1) {
            mu = fmaxf(mu, __shfl_xor(mu, o));
            md = fminf(md, __shfl_xor(md, o));
        }
        if (lane == 0) { statg[c] = mu; statg[nc + c] = md; }
    }

    // ---- zero table ----
    {
        float2* S2 = (float2*)S;
        const int tot2 = (W * SP) >> 1;
        for (int k = tid; k < tot2; k += blockDim.x) S2[k] = make_float2(0.f, 0.f);
    }
    __syncthreads();

    // ---- fill softplus(raw[p]) at S[(j+1)*SP + (i+1)] ----
    for (int p = tid; p < n; p += blockDim.x) {
        const float disc = (float)((2 * L + 1) * (2 * L + 1)) - 8.0f * (float)p;
        int i = (int)(((float)(2 * L + 1) - sqrtf(disc)) * 0.5f);
        i = max(0, min(i, L - 1));
        while (i + 1 <= L - 1 && ((i + 1) * (2 * L + 1 - (i + 1))) / 2 <= p) ++i;
        while (i > 0 && (i * (2 * L + 1 - i)) / 2 > p) --i;
        const int j = i + (p - (i * (2 * L + 1 - i)) / 2);
        S[(j + 1) * SP + (i + 1)] = softplus_f(raw[p]);
    }
    __syncthreads();

    // ---- row prefix over b (2 passes x 8 waves x 16 rows; 4 segs of 52) ----
    for (int pass = 0; pass < 2; ++pass) {
        const int a  = pass * 128 + wid * 16 + r16;   // 0..255 over 2 passes
        const int b0 = seg * 52;
        const bool act = (a <= L);
        float2 v[26];
        float ssum = 0.0f;
        if (act) {
#pragma unroll
            for (int k = 0; k < 26; ++k) {
                const int b = b0 + 2 * k;
                float2 t2 = (b < SP) ? *(const float2*)&S[a * SP + b]
                                     : make_float2(0.f, 0.f);
                v[k] = t2;
                ssum += t2.x + t2.y;
            }
        }
        float excl = 0.0f;
#pragma unroll
        for (int k = 0; k < 3; ++k) {
            const float sk = __shfl(ssum, r16 + 16 * k);
            if (seg > k) excl += sk;
        }
        if (act) {
            float run = excl;
#pragma unroll
            for (int k = 0; k < 26; ++k) {
                const int b = b0 + 2 * k;
                if (b < SP) {
                    run += v[k].x; const float rx = run;
                    run += v[k].y; const float ry = run;
                    *(float2*)&S[a * SP + b] = make_float2(rx, ry);
                }
            }
        }
    }
    __syncthreads();

    // ---- column prefix over a: float2 column-pair per 16-lane group,
    //      13 rows per lane (16*13 = 208 >= 201); 32 groups, 4 passes ----
    {
        const int gid = wid * 4 + seg;      // 0..31
        const int a0  = r16 * 13;
        for (int cp = gid; cp < (SP >> 1); cp += 32) {
            const int b = 2 * cp;
            float2 v[13];
            float sx = 0.0f, sy = 0.0f;
#pragma unroll
            for (int k = 0; k < 13; ++k) {
                const int a = a0 + k;
                float2 t2 = (a < W) ? *(const float2*)&S[a * SP + b]
                                    : make_float2(0.f, 0.f);
                v[k] = t2;
                sx += t2.x; sy += t2.y;
            }
            float ix = sx, iy = sy;
            for (int o = 1; o < 16; o <<= 1) {
                const float tx = __shfl_up(ix, o);
                const float ty = __shfl_up(iy, o);
                if (r16 >= o) { ix += tx; iy += ty; }
            }
            float rx = ix - sx, ry = iy - sy;
#pragma unroll
            for (int k = 0; k < 13; ++k) {
                const int a = a0 + k;
                if (a < W) {
                    rx += v[k].x; ry += v[k].y;
                    *(float2*)&S[a * SP + b] = make_float2(rx, ry);
                }
            }
        }
    }
    __syncthreads();

    // ---- write table to global (coalesced float2) ----
    {
        float2* Cg2 = (float2*)Cg;
        float2* S2  = (float2*)S;
        const int tot2 = (W * SP) >> 1;
        for (int k = tid; k < tot2; k += blockDim.x) Cg2[k] = S2[k];
    }
}

__global__ __launch_bounds__(256) void hyst_main(
    const float* __restrict__ h,
    const float* __restrict__ mesh,
    const float* __restrict__ Cg,
    const float* __restrict__ statg,
    const float* __restrict__ scale,
    const float* __restrict__ offset,
    float* __restrict__ out,
    int T, int L, int n)
{
    const int W  = L + 1;
    const int SP = (W + 1) & ~1;
    const int nc = (T + 63) >> 6;

    const int lane = threadIdx.x & 63;
    const int wid  = threadIdx.x >> 6;
    const int t = blockIdx.x * (blockDim.x >> 6) + wid;
    if (t >= T) return;

    // xs levels: lane holds levels lane, +64, +128, +192
    float xsr[4];
#pragma unroll
    for (int k = 0; k < 4; ++k) {
        const int jj = lane + 64 * k;
        xsr[k] = (jj < L) ? mesh[2 * jj + 1] : 2.0f;  // 2.0 never matches
    }

    float u_max = -1.0f, d_min = 2.0f;
    int Acov = 0, Bcov = L;
    int nrec = 0;                 // wave-uniform
    int r_up = 0, r_lo = 0, r_Ap = 0, r_Bp = 0;   // per-lane record slot
    float acc = 0.0f;             // per-lane deferred contributions

    auto flushrec = [&]() {
        if (lane < nrec) {
            float contrib;
            if (r_up) {
                contrib = Cg[r_lo * SP + r_Bp] - Cg[r_Ap * SP + r_Bp];
            } else {
                contrib = -((Cg[L * SP + r_Bp] - Cg[L * SP + r_lo])
                          - (Cg[r_Ap * SP + r_Bp] - Cg[r_Ap * SP + r_lo]));
            }
            acc += contrib;
        }
        nrec = 0;
    };
    auto count_le = [&](float v) -> int {
        return __popcll(__ballot(xsr[0] <= v)) + __popcll(__ballot(xsr[1] <= v))
             + __popcll(__ballot(xsr[2] <= v)) + __popcll(__ballot(xsr[3] <= v));
    };
    auto count_lt = [&](float v) -> int {
        return __popcll(__ballot(xsr[0] < v)) + __popcll(__ballot(xsr[1] < v))
             + __popcll(__ballot(xsr[2] < v)) + __popcll(__ballot(xsr[3] < v));
    };
    auto process_chunk = [&](int c) {
        const int i = (c << 6) + lane;
        const int ic = (i < T) ? i : (T - 1);
        const float hv = h[ic];
        const float hp = (ic > 0) ? h[ic - 1] : 0.0f;
        const bool valid = (i <= t);
        const bool isup = valid && (hv > hp);
        const bool isdn = valid && (hv < hp);
        unsigned long long mup = __ballot(isup && hv > u_max);
        unsigned long long mdn = __ballot(isdn && hv < d_min);
        unsigned long long m = mup | mdn;
        while (m) {
            const int rl = 63 - __builtin_clzll(m);   // largest i first
            const float v = __shfl(hv, rl);
            if ((mup >> rl) & 1ull) {
                u_max = v;
                const int lo = count_le(v);
                if (lo > Acov) {
                    if (lane == nrec) { r_up = 1; r_lo = lo; r_Ap = Acov; r_Bp = Bcov; }
                    ++nrec;
                    Acov = lo;
                    if (nrec == 64) flushrec();
                }
            } else {
                d_min = v;
                const int lo = count_lt(v);
                if (lo < Bcov) {
                    if (lane == nrec) { r_up = 0; r_lo = lo; r_Ap = Acov; r_Bp = Bcov; }
                    ++nrec;
                    Bcov = lo;
                    if (nrec == 64) flushrec();
                }
            }
            const unsigned long long below =
                (rl == 0) ? 0ull : ((1ull << rl) - 1ull);
            mup = __ballot(isup && hv > u_max) & below;
            mdn = __ballot(isdn && hv < d_min) & below;
            m = mup | mdn;
        }
    };

    const int ct = t >> 6;
    process_chunk(ct);  // partial top chunk (valid mask), exact

    for (int g = (ct - 1) >> 6; g >= 0; --g) {   // ct==0 -> skipped
        if (Acov >= L || Bcov <= 0) break;
        const int cbase = g << 6;
        const int c = cbase + lane;
        const bool act = (c < ct);
        const float vu = act ? statg[c] : -1.0f;
        const float vd = act ? statg[nc + c] : 2.0f;
        // suffix scans (higher lanes = later chunks in backward order)
        float su = vu, sd = vd;
        for (int o = 1; o < 64; o <<= 1) {
            su = fmaxf(su, __shfl_down(su, o));
            sd = fminf(sd, __shfl_down(sd, o));
        }
        float sue = __shfl_down(su, 1);
        float sde = __shfl_down(sd, 1);
        if (lane == 63) { sue = -1.0f; sde = 2.0f; }
        const bool enter = act && ((vu > fmaxf(u_max, sue)) ||
                                   (vd < fminf(d_min, sde)));
        unsigned long long em = __ballot(enter);
        while (em) {
            const int rl = 63 - __builtin_clzll(em);
            process_chunk(cbase + rl);
            em &= ~(1ull << rl);
            if (Acov >= L || Bcov <= 0) break;
        }
    }

    flushrec();
    // leftover region keeps initial -1
    if (lane == 0) acc -= Cg[L * SP + Bcov] - Cg[Acov * SP + Bcov];
    for (int o = 1; o < 64; o <<= 1) acc += __shfl_xor(acc, o);
    if (lane == 0) out[t] = scale[0] * (acc / (float)n) + offset[0];
}

extern "C" void kernel_launch(void* const* d_in, const int* in_sizes, int n_in,
                              void* d_out, int out_size, void* d_ws, size_t ws_size,
                              hipStream_t stream) {
    const float* h      = (const float*)d_in[0];
    const float* mesh   = (const float*)d_in[1];
    const float* raw    = (const float*)d_in[2];
    const float* scale  = (const float*)d_in[3];
    const float* offset = (const float*)d_in[4];
    float* out = (float*)d_out;

    const int T = in_sizes[0];
    const int n = in_sizes[2];
    const int L = (int)((sqrt(8.0 * (double)n + 1.0) - 1.0) / 2.0 + 0.5);
    const int W = L + 1;
    const int SP = (W + 1) & ~1;
    const int nc = (T + 63) / 64;

    float* Cg    = (float*)d_ws;              // W*SP floats
    float* statg = Cg + (size_t)W * SP;       // 2*nc floats

    const size_t shmem = (size_t)W * SP * sizeof(float);  // 162,408 B
    (void)hipFuncSetAttribute(reinterpret_cast<const void*>(build_table),
                              hipFuncAttributeMaxDynamicSharedMemorySize,
                              (int)shmem);

    hipLaunchKernelGGL(build_table, dim3(1), dim3(512), shmem, stream,
                       h, raw, Cg, statg, T, L, n);

    const int nwv = 4;                         // 256 threads = 4 waves
    const int grid = (T + nwv - 1) / nwv;      // 1024 blocks
    hipLaunchKernelGGL(hyst_main, dim3(grid), dim3(256), 0, stream,
                       h, mesh, Cg, statg, scale, offset, out, T, L, n);
}

// Round 7
// 26.140 us; speedup vs baseline: 2.8998x; 2.8998x over previous
//
#include <hip/hip_runtime.h>
#include <math.h>

// Preisach hysteresis, three small kernels (all multi-block, no big register
// arrays -- rounds 4-6 showed 1-block LDS builds with float2 v[26] arrays
// spill to scratch and run 57-75us latency-bound on one CU):
//  1) build_rows_stats: wave per row j -- softplus + shfl inclusive scan over
//     beta, row prefixes written to global Cg. Extra blocks: per-64-chunk
//     up-move-max / down-move-min stats.
//  2) build_cols: wave per column b -- shfl scan + carry over alpha (4 values
//     per lane, registers only).
//  3) hyst_main (wave per t): exact backward-record scan with parallel chunk
//     filter; table lookups deferred, issued one-record-per-lane in parallel.
//
// Table: C[a][b] = sum_{alpha_idx<a, beta_idx<b, beta<=alpha} softplus(raw),
// a,b in [0,L], row-major stride SP=202. packed p(i,j)=L*i-i(i-1)/2+(j-i).

__device__ __forceinline__ float softplus_f(float x) {
    return fmaxf(x, 0.0f) + log1pf(expf(-fabsf(x)));
}

__global__ __launch_bounds__(256) void build_rows_stats(
    const float* __restrict__ h,
    const float* __restrict__ raw,
    float* __restrict__ Cg,      // W*SP floats
    float* __restrict__ statg,   // 2*nc floats
    int T, int L, int n, int nrowblocks)
{
    const int W  = L + 1;
    const int SP = (W + 1) & ~1;
    const int nc = (T + 63) >> 6;

    const int lane = threadIdx.x & 63;
    const int wid  = threadIdx.x >> 6;
    const int nwv  = blockDim.x >> 6;   // 4

    if ((int)blockIdx.x < nrowblocks) {
        // ---- row prefix: one wave per row j ----
        const int j = blockIdx.x * nwv + wid;
        if (j >= L) return;
        float* row = Cg + (size_t)(j + 1) * SP;
        float carry = 0.0f;
        for (int k = 0; 64 * k <= j; ++k) {
            const int i = lane + 64 * k;     // beta index
            float d = 0.0f;
            if (i <= j) {
                const int p = L * i - (i * (i - 1)) / 2 + (j - i);
                d = softplus_f(raw[p]);
            }
            float x = d;
            for (int o = 1; o < 64; o <<= 1) {
                const float tv = __shfl_up(x, o);
                if (lane >= o) x += tv;
            }
            if (i <= j) row[i + 1] = x + carry;
            carry += __shfl(x, 63);
        }
        const float total = carry;
        for (int b = j + 2 + lane; b <= L; b += 64) row[b] = total;
        if (lane == 0) row[0] = 0.0f;
        if (j == 0) {
            for (int b = lane; b <= L; b += 64) Cg[b] = 0.0f;  // row a=0
        }
    } else {
        // ---- per-chunk up-move max / down-move min ----
        const int c = ((int)blockIdx.x - nrowblocks) * nwv + wid;
        if (c >= nc) return;
        const int i = (c << 6) + lane;
        const bool inb = (i < T);
        const float hv = inb ? h[i] : 0.0f;
        const float hp = (inb && i > 0) ? h[i - 1] : 0.0f;
        float mu = (inb && hv > hp) ? hv : -1.0f;
        float md = (inb && hv < hp) ? hv : 2.0f;
        for (int o = 1; o < 64; o <<= 1) {
            mu = fmaxf(mu, __shfl_xor(mu, o));
            md = fminf(md, __shfl_xor(md, o));
        }
        if (lane == 0) { statg[c] = mu; statg[nc + c] = md; }
    }
}

__global__ __launch_bounds__(256) void build_cols(
    float* __restrict__ Cg, int L)
{
    const int W  = L + 1;
    const int SP = (W + 1) & ~1;
    const int lane = threadIdx.x & 63;
    const int b = blockIdx.x * (blockDim.x >> 6) + (threadIdx.x >> 6);  // column
    if (b >= W) return;

    float carry = 0.0f;
    for (int k = 0; k < 4; ++k) {                // rows a = 1..L (<= 256)
        const int a = 1 + lane + 64 * k;
        float x = (a <= L) ? Cg[(size_t)a * SP + b] : 0.0f;
        for (int o = 1; o < 64; o <<= 1) {
            const float tv = __shfl_up(x, o);
            if (lane >= o) x += tv;
        }
        if (a <= L) Cg[(size_t)a * SP + b] = x + carry;
        carry += __shfl(x, 63);
    }
}

__global__ __launch_bounds__(256) void hyst_main(
    const float* __restrict__ h,
    const float* __restrict__ mesh,
    const float* __restrict__ Cg,
    const float* __restrict__ statg,
    const float* __restrict__ scale,
    const float* __restrict__ offset,
    float* __restrict__ out,
    int T, int L, int n)
{
    const int W  = L + 1;
    const int SP = (W + 1) & ~1;
    const int nc = (T + 63) >> 6;

    const int lane = threadIdx.x & 63;
    const int wid  = threadIdx.x >> 6;
    const int t = blockIdx.x * (blockDim.x >> 6) + wid;
    if (t >= T) return;

    // xs levels: lane holds levels lane, +64, +128, +192
    float xsr[4];
#pragma unroll
    for (int k = 0; k < 4; ++k) {
        const int jj = lane + 64 * k;
        xsr[k] = (jj < L) ? mesh[2 * jj + 1] : 2.0f;  // 2.0 never matches
    }

    float u_max = -1.0f, d_min = 2.0f;
    int Acov = 0, Bcov = L;
    int nrec = 0;                 // wave-uniform
    int r_up = 0, r_lo = 0, r_Ap = 0, r_Bp = 0;   // per-lane record slot
    float acc = 0.0f;             // per-lane deferred contributions

    auto flushrec = [&]() {
        if (lane < nrec) {
            float contrib;
            if (r_up) {
                contrib = Cg[r_lo * SP + r_Bp] - Cg[r_Ap * SP + r_Bp];
            } else {
                contrib = -((Cg[L * SP + r_Bp] - Cg[L * SP + r_lo])
                          - (Cg[r_Ap * SP + r_Bp] - Cg[r_Ap * SP + r_lo]));
            }
            acc += contrib;
        }
        nrec = 0;
    };
    auto count_le = [&](float v) -> int {
        return __popcll(__ballot(xsr[0] <= v)) + __popcll(__ballot(xsr[1] <= v))
             + __popcll(__ballot(xsr[2] <= v)) + __popcll(__ballot(xsr[3] <= v));
    };
    auto count_lt = [&](float v) -> int {
        return __popcll(__ballot(xsr[0] < v)) + __popcll(__ballot(xsr[1] < v))
             + __popcll(__ballot(xsr[2] < v)) + __popcll(__ballot(xsr[3] < v));
    };
    auto process_chunk = [&](int c) {
        const int i = (c << 6) + lane;
        const int ic = (i < T) ? i : (T - 1);
        const float hv = h[ic];
        const float hp = (ic > 0) ? h[ic - 1] : 0.0f;
        const bool valid = (i <= t);
        const bool isup = valid && (hv > hp);
        const bool isdn = valid && (hv < hp);
        unsigned long long mup = __ballot(isup && hv > u_max);
        unsigned long long mdn = __ballot(isdn && hv < d_min);
        unsigned long long m = mup | mdn;
        while (m) {
            const int rl = 63 - __builtin_clzll(m);   // largest i first
            const float v = __shfl(hv, rl);
            if ((mup >> rl) & 1ull) {
                u_max = v;
                const int lo = count_le(v);
                if (lo > Acov) {
                    if (lane == nrec) { r_up = 1; r_lo = lo; r_Ap = Acov; r_Bp = Bcov; }
                    ++nrec;
                    Acov = lo;
                    if (nrec == 64) flushrec();
                }
            } else {
                d_min = v;
                const int lo = count_lt(v);
                if (lo < Bcov) {
                    if (lane == nrec) { r_up = 0; r_lo = lo; r_Ap = Acov; r_Bp = Bcov; }
                    ++nrec;
                    Bcov = lo;
                    if (nrec == 64) flushrec();
                }
            }
            const unsigned long long below =
                (rl == 0) ? 0ull : ((1ull << rl) - 1ull);
            mup = __ballot(isup && hv > u_max) & below;
            mdn = __ballot(isdn && hv < d_min) & below;
            m = mup | mdn;
        }
    };

    const int ct = t >> 6;
    process_chunk(ct);  // partial top chunk (valid mask), exact

    for (int g = (ct - 1) >> 6; g >= 0; --g) {   // ct==0 -> skipped
        if (Acov >= L || Bcov <= 0) break;
        const int cbase = g << 6;
        const int c = cbase + lane;
        const bool act = (c < ct);
        const float vu = act ? statg[c] : -1.0f;
        const float vd = act ? statg[nc + c] : 2.0f;
        // suffix scans (higher lanes = later chunks in backward order)
        float su = vu, sd = vd;
        for (int o = 1; o < 64; o <<= 1) {
            su = fmaxf(su, __shfl_down(su, o));
            sd = fminf(sd, __shfl_down(sd, o));
        }
        float sue = __shfl_down(su, 1);
        float sde = __shfl_down(sd, 1);
        if (lane == 63) { sue = -1.0f; sde = 2.0f; }
        const bool enter = act && ((vu > fmaxf(u_max, sue)) ||
                                   (vd < fminf(d_min, sde)));
        unsigned long long em = __ballot(enter);
        while (em) {
            const int rl = 63 - __builtin_clzll(em);
            process_chunk(cbase + rl);
            em &= ~(1ull << rl);
            if (Acov >= L || Bcov <= 0) break;
        }
    }

    flushrec();
    // leftover region keeps initial -1
    if (lane == 0) acc -= Cg[L * SP + Bcov] - Cg[Acov * SP + Bcov];
    for (int o = 1; o < 64; o <<= 1) acc += __shfl_xor(acc, o);
    if (lane == 0) out[t] = scale[0] * (acc / (float)n) + offset[0];
}

extern "C" void kernel_launch(void* const* d_in, const int* in_sizes, int n_in,
                              void* d_out, int out_size, void* d_ws, size_t ws_size,
                              hipStream_t stream) {
    const float* h      = (const float*)d_in[0];
    const float* mesh   = (const float*)d_in[1];
    const float* raw    = (const float*)d_in[2];
    const float* scale  = (const float*)d_in[3];
    const float* offset = (const float*)d_in[4];
    float* out = (float*)d_out;

    const int T = in_sizes[0];
    const int n = in_sizes[2];
    const int L = (int)((sqrt(8.0 * (double)n + 1.0) - 1.0) / 2.0 + 0.5);
    const int W = L + 1;
    const int SP = (W + 1) & ~1;
    const int nc = (T + 63) / 64;

    float* Cg    = (float*)d_ws;              // W*SP floats
    float* statg = Cg + (size_t)W * SP;       // 2*nc floats

    // rows + chunk stats: wave per row / wave per chunk
    const int nrowblocks  = (L + 3) / 4;       // 4 waves per 256-thread block
    const int nstatblocks = (nc + 3) / 4;
    hipLaunchKernelGGL(build_rows_stats, dim3(nrowblocks + nstatblocks),
                       dim3(256), 0, stream, h, raw, Cg, statg, T, L, n,
                       nrowblocks);

    // columns: wave per column
    const int ncolblocks = (W + 3) / 4;
    hipLaunchKernelGGL(build_cols, dim3(ncolblocks), dim3(256), 0, stream,
                       Cg, L);

    // main: wave per t
    const int nwv = 4;                         // 256 threads = 4 waves
    const int grid = (T + nwv - 1) / nwv;      // 1024 blocks
    hipLaunchKernelGGL(hyst_main, dim3(grid), dim3(256), 0, stream,
                       h, mesh, Cg, statg, scale, offset, out, T, L, n);
}